// Round 1
// baseline (376.335 us; speedup 1.0000x reference)
//
#include <hip/hip_runtime.h>

#define NGT 30000
#define NBLK_G 118          // ceil(30000/256)
#define PART_STRIDE 128

// ---------------------------------------------------------------------------
// Kernel 1: chamfer distances between gt points (30000) and pbd[m] clouds.
//   grid = (NBLK_G, 3), block = 256
//   Phase 1: thread-per-gt min over all preds (in LDS) -> block sum -> partials
//   Phase 2: thread-per-pred min over this block's 256 gt points (in LDS)
//            -> global atomicMin on float bits (all values >= 0)
// ---------------------------------------------------------------------------
__global__ __launch_bounds__(256) void chamfer_kernel(
    const float* __restrict__ gt,
    const float* __restrict__ pbd0,
    const float* __restrict__ pbd1,
    const float* __restrict__ pbd2,
    float* __restrict__ predmin,    // [3240] pre-init to ~3.39e38 (0x7f bytes)
    float* __restrict__ partials)   // [3 * PART_STRIDE]
{
    __shared__ float spred[2466 * 3];
    __shared__ float sgt[256 * 3];
    __shared__ float sred[4];

    const int tid = threadIdx.x;
    const int m = blockIdx.y;
    const float* pred = (m == 0) ? pbd0 : (m == 1) ? pbd1 : pbd2;
    const int n       = (m == 0) ? 156  : (m == 1) ? 618  : 2466;
    const int poff    = (m == 0) ? 0    : (m == 1) ? 156  : 774;

    for (int i = tid; i < n * 3; i += 256) spred[i] = pred[i];

    const int g = blockIdx.x * 256 + tid;
    const bool gvalid = (g < NGT);
    float gx = 1e18f, gy = 1e18f, gz = 1e18f;   // sentinel: huge but finite dist
    if (gvalid) { gx = gt[3*g+0]; gy = gt[3*g+1]; gz = gt[3*g+2]; }
    sgt[3*tid+0] = gx; sgt[3*tid+1] = gy; sgt[3*tid+2] = gz;
    __syncthreads();

    // ---- phase 1: dist1 (min over preds for each gt point) ----
    float mymin = 3.0e38f;
    if (gvalid) {
        #pragma unroll 4
        for (int j = 0; j < n; ++j) {
            float dx = gx - spred[3*j+0];
            float dy = gy - spred[3*j+1];
            float dz = gz - spred[3*j+2];
            float d = dx*dx + dy*dy + dz*dz;
            mymin = fminf(mymin, d);
        }
    }
    float c1 = gvalid ? mymin : 0.0f;
    for (int off = 32; off; off >>= 1) c1 += __shfl_down(c1, off, 64);
    const int lane = tid & 63, wid = tid >> 6;
    if (lane == 0) sred[wid] = c1;
    __syncthreads();
    if (tid == 0)
        partials[m * PART_STRIDE + blockIdx.x] = sred[0] + sred[1] + sred[2] + sred[3];

    // ---- phase 2: dist2 (min over this gt chunk for each pred point) ----
    for (int j = tid; j < n; j += 256) {
        const float px = spred[3*j+0], py = spred[3*j+1], pz = spred[3*j+2];
        float mn = 3.0e38f;
        #pragma unroll 4
        for (int k = 0; k < 256; ++k) {
            float dx = sgt[3*k+0] - px;
            float dy = sgt[3*k+1] - py;
            float dz = sgt[3*k+2] - pz;
            float d = dx*dx + dy*dy + dz*dz;
            mn = fminf(mn, d);
        }
        atomicMin((int*)(predmin + poff + j), __float_as_int(mn));
    }
}

// ---------------------------------------------------------------------------
// Kernel 2: everything else + final combine. 1 block x 1024 threads.
// ---------------------------------------------------------------------------
__global__ __launch_bounds__(1024) void finalize_kernel(
    const float* __restrict__ pc0, const float* __restrict__ pc1, const float* __restrict__ pc2,
    const float* __restrict__ pbd0, const float* __restrict__ pbd1, const float* __restrict__ pbd2,
    const int* __restrict__ ed0, const int* __restrict__ ed1, const int* __restrict__ ed2,
    const int* __restrict__ li0, const int* __restrict__ li1, const int* __restrict__ li2,
    const float* __restrict__ predmin, const float* __restrict__ partials,
    float* __restrict__ out)
{
    const int tid = threadIdx.x;
    __shared__ float sred[16];

    const int   NVs[3]   = {156, 618, 2466};
    const int   NEs[3]   = {462, 1848, 7392};
    const int   poffs[3] = {0, 156, 774};
    const float lapc[3]  = {0.2f, 1.0f, 1.0f};
    const float* pcs[3]  = {pc0, pc1, pc2};
    const float* pbds[3] = {pbd0, pbd1, pbd2};
    const int*   eds[3]  = {ed0, ed1, ed2};
    const int*   lis[3]  = {li0, li1, li2};

    float chacc = 0.f, edacc = 0.f, lapacc = 0.f;

    // dist1 block partials (sum / 30000)
    for (int i = tid; i < 3 * NBLK_G; i += 1024) {
        int m = i / NBLK_G, b = i % NBLK_G;
        chacc += partials[m * PART_STRIDE + b] * (1.0f / 30000.0f);
    }
    // dist2 per-pred mins (sum / n)
    for (int m = 0; m < 3; ++m) {
        const float inv = 1.0f / (float)NVs[m];
        for (int j = tid; j < NVs[m]; j += 1024)
            chacc += predmin[poffs[m] + j] * inv;
    }
    // edge regularization (uses pred_coord)
    for (int m = 0; m < 3; ++m) {
        const float s = 300.0f / (float)NEs[m];
        const int* E = eds[m];
        const float* P = pcs[m];
        for (int e = tid; e < NEs[m]; e += 1024) {
            int a = E[2*e], b = E[2*e+1];
            float dx = P[3*a+0] - P[3*b+0];
            float dy = P[3*a+1] - P[3*b+1];
            float dz = P[3*a+2] - P[3*b+2];
            edacc += (dx*dx + dy*dy + dz*dz) * s;
        }
    }
    // laplace regularization: d_v = m_v - (sum_nbr m)/deg, m = pbd - pred
    for (int m = 0; m < 3; ++m) {
        const float s = lapc[m] / (float)NVs[m];
        const int* L = lis[m];
        const float* PB = pbds[m];
        const float* PC = pcs[m];
        for (int v = tid; v < NVs[m]; v += 1024) {
            float mvx = PB[3*v+0] - PC[3*v+0];
            float mvy = PB[3*v+1] - PC[3*v+1];
            float mvz = PB[3*v+2] - PC[3*v+2];
            float sx = 0.f, sy = 0.f, sz = 0.f;
            #pragma unroll
            for (int k = 0; k < 8; ++k) {
                int nb = L[10*v + k];
                if (nb >= 0) {
                    sx += PB[3*nb+0] - PC[3*nb+0];
                    sy += PB[3*nb+1] - PC[3*nb+1];
                    sz += PB[3*nb+2] - PC[3*nb+2];
                }
            }
            float invdeg = 1.0f / (float)L[10*v + 9];
            float dx = mvx - sx * invdeg;
            float dy = mvy - sy * invdeg;
            float dz = mvz - sz * invdeg;
            float t = dx*dx + dy*dy + dz*dz;
            if (m > 0) t += mvx*mvx + mvy*mvy + mvz*mvz;   // move loss
            lapacc += t * s;
        }
    }

    // three block reductions; result valid in thread 0
    auto reduce = [&](float v) -> float {
        for (int off = 32; off; off >>= 1) v += __shfl_down(v, off, 64);
        const int lane = tid & 63, wid = tid >> 6;
        __syncthreads();
        if (lane == 0) sred[wid] = v;
        __syncthreads();
        float r = 0.f;
        if (wid == 0) {
            r = (lane < 16) ? sred[lane] : 0.f;
            for (int off = 8; off; off >>= 1) r += __shfl_down(r, off, 64);
        }
        return r;
    };

    float ch = reduce(chacc);
    float ed = reduce(edacc);
    float lp = reduce(lapacc);

    if (tid == 0) {
        out[0] = 100.0f * ch + 0.1f * ed + 0.3f * lp;
        out[1] = ch;
        out[2] = ed;
        out[3] = lp;
    }
}

extern "C" void kernel_launch(void* const* d_in, const int* in_sizes, int n_in,
                              void* d_out, int out_size, void* d_ws, size_t ws_size,
                              hipStream_t stream) {
    const float* gt   = (const float*)d_in[0];
    const float* pc0  = (const float*)d_in[1];
    const float* pbd0 = (const float*)d_in[2];
    const int*   ed0  = (const int*)  d_in[3];
    const int*   li0  = (const int*)  d_in[4];
    const float* pc1  = (const float*)d_in[5];
    const float* pbd1 = (const float*)d_in[6];
    const int*   ed1  = (const int*)  d_in[7];
    const int*   li1  = (const int*)  d_in[8];
    const float* pc2  = (const float*)d_in[9];
    const float* pbd2 = (const float*)d_in[10];
    const int*   ed2  = (const int*)  d_in[11];
    const int*   li2  = (const int*)  d_in[12];

    float* ws       = (float*)d_ws;
    float* predmin  = ws;            // 3240 floats
    float* partials = ws + 3240;     // 3 * PART_STRIDE floats
    float* out      = (float*)d_out;

    // init per-pred mins to 0x7f7f7f7f ~= 3.39e38 (positive, atomicMin-safe)
    hipMemsetAsync(predmin, 0x7f, 3240 * sizeof(float), stream);

    dim3 grid(NBLK_G, 3);
    chamfer_kernel<<<grid, 256, 0, stream>>>(gt, pbd0, pbd1, pbd2, predmin, partials);

    finalize_kernel<<<1, 1024, 0, stream>>>(pc0, pc1, pc2, pbd0, pbd1, pbd2,
                                            ed0, ed1, ed2, li0, li1, li2,
                                            predmin, partials, out);
}

// Round 2
// 159.417 us; speedup vs baseline: 2.3607x; 2.3607x over previous
//
#include <hip/hip_runtime.h>

#define NGT 30000
#define GT_TILE 1024
#define NBLK_G 30            // ceil(30000/1024)
#define NCHUNK 14            // pred chunks of 256: m0:1, m1:3, m2:10

// ---------------------------------------------------------------------------
// Chamfer: grid = (NBLK_G, NCHUNK), block = 256.
// Each block: gt tile of 1024 (4 pts/thread in registers + float4 LDS copy)
// x pred chunk of <=256 (float4 LDS).
// Phase 1: per-thread min over chunk preds for its 4 gt pts -> atomicMin gtmin.
// Phase 2: per-thread (one pred) min over the 1024-gt tile  -> atomicMin predmin.
// All atomicMin are int-on-float-bits; values >= 0 so ordering is exact.
// ---------------------------------------------------------------------------
__global__ __launch_bounds__(256) void chamfer_kernel(
    const float* __restrict__ gt,
    const float* __restrict__ pbd0,
    const float* __restrict__ pbd1,
    const float* __restrict__ pbd2,
    float* __restrict__ gtmin,     // [3*30000] pre-init 0x7f bytes
    float* __restrict__ predmin)   // [3240]    pre-init 0x7f bytes
{
    __shared__ float4 spred[256];
    __shared__ float4 sgt[GT_TILE];

    const int tid = threadIdx.x;
    const int c = blockIdx.y;

    const int mesh = (c == 0) ? 0 : (c < 4 ? 1 : 2);
    const int coff = (c == 0) ? 0 : (c < 4 ? (c - 1) * 256 : (c - 4) * 256);
    const int n    = (mesh == 0) ? 156 : (mesh == 1) ? 618 : 2466;
    const int poff = (mesh == 0) ? 0   : (mesh == 1) ? 156 : 774;
    const float* pred = (mesh == 0) ? pbd0 : (mesh == 1) ? pbd1 : pbd2;
    const int np = min(256, n - coff);

    if (tid < np) {
        const int j = coff + tid;
        spred[tid] = make_float4(pred[3*j+0], pred[3*j+1], pred[3*j+2], 0.0f);
    }

    const int gbase = blockIdx.x * GT_TILE;
    float gx[4], gy[4], gz[4], gmin[4];
    #pragma unroll
    for (int k = 0; k < 4; ++k) {
        const int g = gbase + k * 256 + tid;
        float x = 1e18f, y = 1e18f, z = 1e18f;
        if (g < NGT) { x = gt[3*g+0]; y = gt[3*g+1]; z = gt[3*g+2]; }
        gx[k] = x; gy[k] = y; gz[k] = z; gmin[k] = 3.0e38f;
        sgt[k * 256 + tid] = make_float4(x, y, z, 0.0f);
    }
    __syncthreads();

    // ---- phase 1: gt-side mins over this pred chunk ----
    #pragma unroll 2
    for (int j = 0; j < np; ++j) {
        const float4 p = spred[j];          // broadcast b128
        #pragma unroll
        for (int k = 0; k < 4; ++k) {
            const float dx = gx[k] - p.x;
            const float dy = gy[k] - p.y;
            const float dz = gz[k] - p.z;
            gmin[k] = fminf(gmin[k], dx*dx + dy*dy + dz*dz);
        }
    }
    #pragma unroll
    for (int k = 0; k < 4; ++k) {
        const int g = gbase + k * 256 + tid;
        if (g < NGT)
            atomicMin((int*)(gtmin + mesh * NGT + g), __float_as_int(gmin[k]));
    }

    // ---- phase 2: pred-side mins over this gt tile ----
    if (tid < np) {
        const float4 p = spred[tid];
        float mn = 3.0e38f;
        #pragma unroll 8
        for (int k = 0; k < GT_TILE; ++k) {
            const float4 q = sgt[k];        // broadcast b128
            const float dx = q.x - p.x;
            const float dy = q.y - p.y;
            const float dz = q.z - p.z;
            mn = fminf(mn, dx*dx + dy*dy + dz*dz);
        }
        atomicMin((int*)(predmin + poff + coff + tid), __float_as_int(mn));
    }
}

// ---------------------------------------------------------------------------
// Finalize: reductions + edge + laplace. 1 block x 1024 threads.
// ---------------------------------------------------------------------------
__global__ __launch_bounds__(1024) void finalize_kernel(
    const float* __restrict__ pc0, const float* __restrict__ pc1, const float* __restrict__ pc2,
    const float* __restrict__ pbd0, const float* __restrict__ pbd1, const float* __restrict__ pbd2,
    const int* __restrict__ ed0, const int* __restrict__ ed1, const int* __restrict__ ed2,
    const int* __restrict__ li0, const int* __restrict__ li1, const int* __restrict__ li2,
    const float* __restrict__ gtmin, const float* __restrict__ predmin,
    float* __restrict__ out)
{
    const int tid = threadIdx.x;
    __shared__ float sred[16];

    const int   NVs[3]   = {156, 618, 2466};
    const int   NEs[3]   = {462, 1848, 7392};
    const int   poffs[3] = {0, 156, 774};
    const float lapc[3]  = {0.2f, 1.0f, 1.0f};
    const float* pcs[3]  = {pc0, pc1, pc2};
    const float* pbds[3] = {pbd0, pbd1, pbd2};
    const int*   eds[3]  = {ed0, ed1, ed2};
    const int*   lis[3]  = {li0, li1, li2};

    float chacc = 0.f, edacc = 0.f, lapacc = 0.f;

    // dist1: mean over NGT for each mesh
    for (int i = tid; i < 3 * NGT; i += 1024)
        chacc += gtmin[i] * (1.0f / (float)NGT);
    // dist2: mean over n preds
    for (int m = 0; m < 3; ++m) {
        const float inv = 1.0f / (float)NVs[m];
        for (int j = tid; j < NVs[m]; j += 1024)
            chacc += predmin[poffs[m] + j] * inv;
    }
    // edge regularization (pred_coord)
    for (int m = 0; m < 3; ++m) {
        const float s = 300.0f / (float)NEs[m];
        const int* E = eds[m];
        const float* P = pcs[m];
        for (int e = tid; e < NEs[m]; e += 1024) {
            int a = E[2*e], b = E[2*e+1];
            float dx = P[3*a+0] - P[3*b+0];
            float dy = P[3*a+1] - P[3*b+1];
            float dz = P[3*a+2] - P[3*b+2];
            edacc += (dx*dx + dy*dy + dz*dz) * s;
        }
    }
    // laplace: d_v = m_v - (sum_nbr m)/deg, m = pbd - pred
    for (int m = 0; m < 3; ++m) {
        const float s = lapc[m] / (float)NVs[m];
        const int* L = lis[m];
        const float* PB = pbds[m];
        const float* PC = pcs[m];
        for (int v = tid; v < NVs[m]; v += 1024) {
            float mvx = PB[3*v+0] - PC[3*v+0];
            float mvy = PB[3*v+1] - PC[3*v+1];
            float mvz = PB[3*v+2] - PC[3*v+2];
            float sx = 0.f, sy = 0.f, sz = 0.f;
            #pragma unroll
            for (int k = 0; k < 8; ++k) {
                int nb = L[10*v + k];
                if (nb >= 0) {
                    sx += PB[3*nb+0] - PC[3*nb+0];
                    sy += PB[3*nb+1] - PC[3*nb+1];
                    sz += PB[3*nb+2] - PC[3*nb+2];
                }
            }
            float invdeg = 1.0f / (float)L[10*v + 9];
            float dx = mvx - sx * invdeg;
            float dy = mvy - sy * invdeg;
            float dz = mvz - sz * invdeg;
            float t = dx*dx + dy*dy + dz*dz;
            if (m > 0) t += mvx*mvx + mvy*mvy + mvz*mvz;
            lapacc += t * s;
        }
    }

    auto reduce = [&](float v) -> float {
        for (int off = 32; off; off >>= 1) v += __shfl_down(v, off, 64);
        const int lane = tid & 63, wid = tid >> 6;
        __syncthreads();
        if (lane == 0) sred[wid] = v;
        __syncthreads();
        float r = 0.f;
        if (wid == 0) {
            r = (lane < 16) ? sred[lane] : 0.f;
            for (int off = 8; off; off >>= 1) r += __shfl_down(r, off, 64);
        }
        return r;
    };

    float ch = reduce(chacc);
    float ed = reduce(edacc);
    float lp = reduce(lapacc);

    if (tid == 0) {
        out[0] = 100.0f * ch + 0.1f * ed + 0.3f * lp;
        out[1] = ch;
        out[2] = ed;
        out[3] = lp;
    }
}

extern "C" void kernel_launch(void* const* d_in, const int* in_sizes, int n_in,
                              void* d_out, int out_size, void* d_ws, size_t ws_size,
                              hipStream_t stream) {
    const float* gt   = (const float*)d_in[0];
    const float* pc0  = (const float*)d_in[1];
    const float* pbd0 = (const float*)d_in[2];
    const int*   ed0  = (const int*)  d_in[3];
    const int*   li0  = (const int*)  d_in[4];
    const float* pc1  = (const float*)d_in[5];
    const float* pbd1 = (const float*)d_in[6];
    const int*   ed1  = (const int*)  d_in[7];
    const int*   li1  = (const int*)  d_in[8];
    const float* pc2  = (const float*)d_in[9];
    const float* pbd2 = (const float*)d_in[10];
    const int*   ed2  = (const int*)  d_in[11];
    const int*   li2  = (const int*)  d_in[12];

    float* ws      = (float*)d_ws;
    float* gtmin   = ws;               // 3*30000 floats
    float* predmin = ws + 3 * NGT;     // 3240 floats
    float* out     = (float*)d_out;

    // init mins to 0x7f7f7f7f ~= 3.39e38 (positive -> int-min on float bits ok)
    hipMemsetAsync(gtmin, 0x7f, (3 * NGT + 3240) * sizeof(float), stream);

    dim3 grid(NBLK_G, NCHUNK);
    chamfer_kernel<<<grid, 256, 0, stream>>>(gt, pbd0, pbd1, pbd2, gtmin, predmin);

    finalize_kernel<<<1, 1024, 0, stream>>>(pc0, pc1, pc2, pbd0, pbd1, pbd2,
                                            ed0, ed1, ed2, li0, li1, li2,
                                            gtmin, predmin, out);
}

// Round 3
// 65.119 us; speedup vs baseline: 5.7792x; 2.4481x over previous
//
#include <hip/hip_runtime.h>

#define NGT 30000
#define GT_TILE 512
#define NBLK_G 59            // ceil(30000/512)
#define CHUNK 128
#define NCHUNK 27            // m0: 2 chunks, m1: 5, m2: 20
#define RB 128               // reduce blocks

// ---------------------------------------------------------------------------
// Chamfer: grid = (NBLK_G, NCHUNK), block = 256.
// gt tile of 512 (2 pts/thread in regs + float4 LDS w/ norm in .w)
// x pred chunk of <=128 (float4 LDS w/ norm in .w).
// d = g2 + p2 - 2*dot; per-side constant hoisted out of the min.
// Phase 1: thread min over chunk preds for its 2 gt pts -> atomicMin gtmin.
// Phase 2: 2 threads per pred, each scans half the gt tile, shfl_xor combine
//          -> atomicMin predmin.
// atomicMin on int bits: values >= 0 (tiny fp-negative slop is harmless at
// our threshold), init 0x7f7f7f7f is a huge positive.
// ---------------------------------------------------------------------------
__global__ __launch_bounds__(256) void chamfer_kernel(
    const float* __restrict__ gt,
    const float* __restrict__ pbd0,
    const float* __restrict__ pbd1,
    const float* __restrict__ pbd2,
    float* __restrict__ gtmin,     // [3*NGT] pre-init 0x7f
    float* __restrict__ predmin)   // [3240]  pre-init 0x7f
{
    __shared__ float4 sgt[GT_TILE];
    __shared__ float4 spred[CHUNK];

    const int tid = threadIdx.x;
    const int c = blockIdx.y;

    int mesh, cidx;
    if (c < 2)      { mesh = 0; cidx = c; }
    else if (c < 7) { mesh = 1; cidx = c - 2; }
    else            { mesh = 2; cidx = c - 7; }
    const int coff = cidx * CHUNK;
    const int n    = (mesh == 0) ? 156 : (mesh == 1) ? 618 : 2466;
    const int poff = (mesh == 0) ? 0   : (mesh == 1) ? 156 : 774;
    const float* pred = (mesh == 0) ? pbd0 : (mesh == 1) ? pbd1 : pbd2;
    const int np = min(CHUNK, n - coff);

    if (tid < CHUNK) {
        float4 v = make_float4(0.f, 0.f, 0.f, 0.f);
        if (tid < np) {
            const int j = coff + tid;
            float px = pred[3*j], py = pred[3*j+1], pz = pred[3*j+2];
            v = make_float4(px, py, pz, px*px + py*py + pz*pz);
        }
        spred[tid] = v;
    }

    const int gbase = blockIdx.x * GT_TILE;
    float gx[2], gy[2], gz[2], g2[2], gmin[2];
    #pragma unroll
    for (int k = 0; k < 2; ++k) {
        const int g = gbase + k * 256 + tid;
        float x = 1e18f, y = 1e18f, z = 1e18f;   // sentinel: huge, finite
        if (g < NGT) { x = gt[3*g]; y = gt[3*g+1]; z = gt[3*g+2]; }
        gx[k] = x; gy[k] = y; gz[k] = z;
        g2[k] = x*x + y*y + z*z;
        gmin[k] = 3.0e38f;
        sgt[k * 256 + tid] = make_float4(x, y, z, g2[k]);
    }
    __syncthreads();

    // ---- phase 1: gt-side min over this pred chunk ----
    #pragma unroll 4
    for (int j = 0; j < np; ++j) {
        const float4 p = spred[j];                 // broadcast b128
        #pragma unroll
        for (int k = 0; k < 2; ++k) {
            float dot = gx[k]*p.x + gy[k]*p.y + gz[k]*p.z;
            float t = __fmaf_rn(dot, -2.0f, p.w);  // p2 - 2*dot
            gmin[k] = fminf(gmin[k], t);
        }
    }
    #pragma unroll
    for (int k = 0; k < 2; ++k) {
        const int g = gbase + k * 256 + tid;
        if (g < NGT)
            atomicMin((int*)(gtmin + mesh * NGT + g),
                      __float_as_int(gmin[k] + g2[k]));
    }

    // ---- phase 2: pred-side min; 2 threads per pred ----
    {
        const int j = tid >> 1;
        const int off = (tid & 1) * 256;
        const float4 p = spred[j];                 // 2-address broadcast
        float mn = 3.0e38f;
        #pragma unroll 4
        for (int k = 0; k < 256; ++k) {
            const float4 q = sgt[off + k];
            float dot = q.x*p.x + q.y*p.y + q.z*p.z;
            float t = __fmaf_rn(dot, -2.0f, q.w);  // g2 - 2*dot
            mn = fminf(mn, t);
        }
        mn = fminf(mn, __shfl_xor(mn, 1, 64));
        if ((tid & 1) == 0 && j < np)
            atomicMin((int*)(predmin + poff + coff + j),
                      __float_as_int(mn + p.w));
    }
}

// ---------------------------------------------------------------------------
// Partial reduce: gtmin/predmin sums + edge + laplace, RB blocks x 256.
// Deterministic: fixed index slices, fixed-order block tree reduce.
// ---------------------------------------------------------------------------
__global__ __launch_bounds__(256) void partial_kernel(
    const float* __restrict__ pc0, const float* __restrict__ pc1, const float* __restrict__ pc2,
    const float* __restrict__ pbd0, const float* __restrict__ pbd1, const float* __restrict__ pbd2,
    const int* __restrict__ ed0, const int* __restrict__ ed1, const int* __restrict__ ed2,
    const int* __restrict__ li0, const int* __restrict__ li1, const int* __restrict__ li2,
    const float* __restrict__ gtmin, const float* __restrict__ predmin,
    float* __restrict__ partials)   // [RB*4]
{
    const int   NVs[3]   = {156, 618, 2466};
    const int   NEs[3]   = {462, 1848, 7392};
    const int   poffs[3] = {0, 156, 774};
    const int   eoffs[3] = {0, 462, 2310};
    const float lapc[3]  = {0.2f, 1.0f, 1.0f};
    const float* pcs[3]  = {pc0, pc1, pc2};
    const float* pbds[3] = {pbd0, pbd1, pbd2};
    const int*   eds[3]  = {ed0, ed1, ed2};
    const int*   lis[3]  = {li0, li1, li2};

    const int tid = threadIdx.x;
    const int stride = gridDim.x * 256;
    float ch = 0.f, ed = 0.f, lp = 0.f;

    // index space: [0,90000) gtmin | [90000,93240) predmin |
    //              [93240,102942) edges | [102942,106182) laplace verts
    for (int idx = blockIdx.x * 256 + tid; idx < 106182; idx += stride) {
        if (idx < 90000) {
            ch += gtmin[idx] * (1.0f / 30000.0f);
        } else if (idx < 93240) {
            int p = idx - 90000;
            int m = (p < 156) ? 0 : (p < 774) ? 1 : 2;
            ch += predmin[p] * (1.0f / (float)NVs[m]);
        } else if (idx < 102942) {
            int e = idx - 93240;
            int m = (e < 462) ? 0 : (e < 2310) ? 1 : 2;
            int el = e - eoffs[m];
            const int* E = eds[m];
            const float* P = pcs[m];
            int a = E[2*el], b = E[2*el+1];
            float dx = P[3*a]   - P[3*b];
            float dy = P[3*a+1] - P[3*b+1];
            float dz = P[3*a+2] - P[3*b+2];
            ed += (dx*dx + dy*dy + dz*dz) * (300.0f / (float)NEs[m]);
        } else {
            int v = idx - 102942;
            int m = (v < 156) ? 0 : (v < 774) ? 1 : 2;
            int vl = v - poffs[m];
            const int* L = lis[m];
            const float* PB = pbds[m];
            const float* PC = pcs[m];
            float mvx = PB[3*vl]   - PC[3*vl];
            float mvy = PB[3*vl+1] - PC[3*vl+1];
            float mvz = PB[3*vl+2] - PC[3*vl+2];
            float sx = 0.f, sy = 0.f, sz = 0.f;
            #pragma unroll
            for (int k = 0; k < 8; ++k) {
                int nb = L[10*vl + k];
                if (nb >= 0) {
                    sx += PB[3*nb]   - PC[3*nb];
                    sy += PB[3*nb+1] - PC[3*nb+1];
                    sz += PB[3*nb+2] - PC[3*nb+2];
                }
            }
            float invdeg = 1.0f / (float)L[10*vl + 9];
            float dx = mvx - sx * invdeg;
            float dy = mvy - sy * invdeg;
            float dz = mvz - sz * invdeg;
            float t = dx*dx + dy*dy + dz*dz;
            if (m > 0) t += mvx*mvx + mvy*mvy + mvz*mvz;
            lp += t * (lapc[m] / (float)NVs[m]);
        }
    }

    __shared__ float sred[12];
    for (int off = 32; off; off >>= 1) {
        ch += __shfl_down(ch, off, 64);
        ed += __shfl_down(ed, off, 64);
        lp += __shfl_down(lp, off, 64);
    }
    const int lane = tid & 63, wid = tid >> 6;
    if (lane == 0) { sred[wid] = ch; sred[4 + wid] = ed; sred[8 + wid] = lp; }
    __syncthreads();
    if (tid == 0) {
        partials[blockIdx.x * 4 + 0] = sred[0] + sred[1] + sred[2] + sred[3];
        partials[blockIdx.x * 4 + 1] = sred[4] + sred[5] + sred[6] + sred[7];
        partials[blockIdx.x * 4 + 2] = sred[8] + sred[9] + sred[10] + sred[11];
    }
}

// ---------------------------------------------------------------------------
// Final: sum RB partials, write 4 outputs. 1 block x 128.
// ---------------------------------------------------------------------------
__global__ __launch_bounds__(128) void final_kernel(
    const float* __restrict__ partials, float* __restrict__ out)
{
    const int tid = threadIdx.x;
    float ch = partials[4*tid], ed = partials[4*tid+1], lp = partials[4*tid+2];
    __shared__ float s[6];
    for (int off = 32; off; off >>= 1) {
        ch += __shfl_down(ch, off, 64);
        ed += __shfl_down(ed, off, 64);
        lp += __shfl_down(lp, off, 64);
    }
    if ((tid & 63) == 0) {
        int w = tid >> 6;
        s[w] = ch; s[2 + w] = ed; s[4 + w] = lp;
    }
    __syncthreads();
    if (tid == 0) {
        float c = s[0] + s[1], e = s[2] + s[3], l = s[4] + s[5];
        out[0] = 100.0f * c + 0.1f * e + 0.3f * l;
        out[1] = c;
        out[2] = e;
        out[3] = l;
    }
}

extern "C" void kernel_launch(void* const* d_in, const int* in_sizes, int n_in,
                              void* d_out, int out_size, void* d_ws, size_t ws_size,
                              hipStream_t stream) {
    const float* gt   = (const float*)d_in[0];
    const float* pc0  = (const float*)d_in[1];
    const float* pbd0 = (const float*)d_in[2];
    const int*   ed0  = (const int*)  d_in[3];
    const int*   li0  = (const int*)  d_in[4];
    const float* pc1  = (const float*)d_in[5];
    const float* pbd1 = (const float*)d_in[6];
    const int*   ed1  = (const int*)  d_in[7];
    const int*   li1  = (const int*)  d_in[8];
    const float* pc2  = (const float*)d_in[9];
    const float* pbd2 = (const float*)d_in[10];
    const int*   ed2  = (const int*)  d_in[11];
    const int*   li2  = (const int*)  d_in[12];

    float* ws       = (float*)d_ws;
    float* gtmin    = ws;                    // 3*NGT floats
    float* predmin  = ws + 3 * NGT;          // 3240 floats
    float* partials = ws + 3 * NGT + 3240;   // RB*4 floats
    float* out      = (float*)d_out;

    hipMemsetAsync(gtmin, 0x7f, (3 * NGT + 3240) * sizeof(float), stream);

    dim3 grid(NBLK_G, NCHUNK);
    chamfer_kernel<<<grid, 256, 0, stream>>>(gt, pbd0, pbd1, pbd2, gtmin, predmin);

    partial_kernel<<<RB, 256, 0, stream>>>(pc0, pc1, pc2, pbd0, pbd1, pbd2,
                                           ed0, ed1, ed2, li0, li1, li2,
                                           gtmin, predmin, partials);

    final_kernel<<<1, 128, 0, stream>>>(partials, out);
}

// Round 4
// 53.498 us; speedup vs baseline: 7.0346x; 1.2172x over previous
//
#include <hip/hip_runtime.h>

#define NGT 30000
#define GT_TILE 1024
#define NBLK_G 30            // ceil(30000/1024)
#define CHUNK 128
#define NCHUNK 27            // m0: 2 chunks, m1: 5, m2: 20
#define RB 128               // reduce blocks

// ---------------------------------------------------------------------------
// Chamfer: grid = (NBLK_G, NCHUNK), block = 256.
//   gt tile 1024 (4 pts/thread in regs, float4+norm LDS copy)
//   pred chunk <=128 (float4+norm LDS).
//   d = g2 + p2 - 2*dot; side constant hoisted out of the min.
// Phase 1: 4 gt pts in regs; one broadcast ds_read_b128 per pred serves
//          4 pairs -> atomicMin gtmin.
// Phase 2: 8-lane groups own 4 preds in regs; lane s scans interleaved
//          slice sgt[k*8+s] (8 distinct float4 addrs/wave -> banks 0..31,
//          conflict-free); each ds_read serves 4 pairs; shfl_xor combine
//          -> atomicMin predmin.
// atomicMin on int bits: values >= 0, init 0x7f7f7f7f (huge positive).
// Min is order-independent -> deterministic.
// ---------------------------------------------------------------------------
__global__ __launch_bounds__(256) void chamfer_kernel(
    const float* __restrict__ gt,
    const float* __restrict__ pbd0,
    const float* __restrict__ pbd1,
    const float* __restrict__ pbd2,
    float* __restrict__ gtmin,     // [3*NGT] pre-init 0x7f
    float* __restrict__ predmin)   // [3240]  pre-init 0x7f
{
    __shared__ float4 sgt[GT_TILE];
    __shared__ float4 spred[CHUNK];

    const int tid = threadIdx.x;
    const int c = blockIdx.y;

    int mesh, cidx;
    if (c < 2)      { mesh = 0; cidx = c; }
    else if (c < 7) { mesh = 1; cidx = c - 2; }
    else            { mesh = 2; cidx = c - 7; }
    const int coff = cidx * CHUNK;
    const int n    = (mesh == 0) ? 156 : (mesh == 1) ? 618 : 2466;
    const int poff = (mesh == 0) ? 0   : (mesh == 1) ? 156 : 774;
    const float* pred = (mesh == 0) ? pbd0 : (mesh == 1) ? pbd1 : pbd2;
    const int np = min(CHUNK, n - coff);

    if (tid < CHUNK) {
        float4 v = make_float4(0.f, 0.f, 0.f, 0.f);
        if (tid < np) {
            const int j = coff + tid;
            float px = pred[3*j], py = pred[3*j+1], pz = pred[3*j+2];
            v = make_float4(px, py, pz, px*px + py*py + pz*pz);
        }
        spred[tid] = v;
    }

    const int gbase = blockIdx.x * GT_TILE;
    float gx[4], gy[4], gz[4], g2[4], gmin[4];
    #pragma unroll
    for (int k = 0; k < 4; ++k) {
        const int g = gbase + k * 256 + tid;
        float x = 1e18f, y = 1e18f, z = 1e18f;   // sentinel: huge, finite
        if (g < NGT) { x = gt[3*g]; y = gt[3*g+1]; z = gt[3*g+2]; }
        gx[k] = x; gy[k] = y; gz[k] = z;
        g2[k] = x*x + y*y + z*z;
        gmin[k] = 3.0e38f;
        sgt[k * 256 + tid] = make_float4(x, y, z, g2[k]);
    }
    __syncthreads();

    // ---- phase 1: gt-side min over this pred chunk (broadcast reads) ----
    #pragma unroll 2
    for (int j = 0; j < np; ++j) {
        const float4 p = spred[j];                 // broadcast b128, free
        #pragma unroll
        for (int k = 0; k < 4; ++k) {
            float dot = gx[k]*p.x + gy[k]*p.y + gz[k]*p.z;
            float t = __fmaf_rn(dot, -2.0f, p.w);  // p2 - 2*dot
            gmin[k] = fminf(gmin[k], t);
        }
    }
    #pragma unroll
    for (int k = 0; k < 4; ++k) {
        const int g = gbase + k * 256 + tid;
        if (g < NGT)
            atomicMin((int*)(gtmin + mesh * NGT + g),
                      __float_as_int(gmin[k] + g2[k]));
    }

    // ---- phase 2: pred-side min; 8-lane groups x 4 preds in regs ----
    {
        const int grp = tid >> 3;                  // 0..31 -> preds 4g..4g+3
        const int s   = tid & 7;                   // scan slice
        float4 p[4];
        #pragma unroll
        for (int r = 0; r < 4; ++r) p[r] = spred[4*grp + r];
        float mn[4] = {3.0e38f, 3.0e38f, 3.0e38f, 3.0e38f};
        #pragma unroll 2
        for (int k = 0; k < GT_TILE / 8; ++k) {
            const float4 q = sgt[k * 8 + s];       // 8 addrs -> banks 0..31
            #pragma unroll
            for (int r = 0; r < 4; ++r) {
                float dot = q.x*p[r].x + q.y*p[r].y + q.z*p[r].z;
                float t = __fmaf_rn(dot, -2.0f, q.w);  // g2 - 2*dot
                mn[r] = fminf(mn[r], t);
            }
        }
        #pragma unroll
        for (int off = 1; off < 8; off <<= 1) {
            #pragma unroll
            for (int r = 0; r < 4; ++r)
                mn[r] = fminf(mn[r], __shfl_xor(mn[r], off, 64));
        }
        if (s == 0) {
            #pragma unroll
            for (int r = 0; r < 4; ++r) {
                const int pj = 4*grp + r;
                if (pj < np)
                    atomicMin((int*)(predmin + poff + coff + pj),
                              __float_as_int(mn[r] + p[r].w));
            }
        }
    }
}

// ---------------------------------------------------------------------------
// Partial reduce: gtmin/predmin sums + edge + laplace, RB blocks x 256.
// Deterministic: fixed index slices, fixed-order block tree reduce.
// ---------------------------------------------------------------------------
__global__ __launch_bounds__(256) void partial_kernel(
    const float* __restrict__ pc0, const float* __restrict__ pc1, const float* __restrict__ pc2,
    const float* __restrict__ pbd0, const float* __restrict__ pbd1, const float* __restrict__ pbd2,
    const int* __restrict__ ed0, const int* __restrict__ ed1, const int* __restrict__ ed2,
    const int* __restrict__ li0, const int* __restrict__ li1, const int* __restrict__ li2,
    const float* __restrict__ gtmin, const float* __restrict__ predmin,
    float* __restrict__ partials)   // [RB*4]
{
    const int   NVs[3]   = {156, 618, 2466};
    const int   NEs[3]   = {462, 1848, 7392};
    const int   poffs[3] = {0, 156, 774};
    const int   eoffs[3] = {0, 462, 2310};
    const float lapc[3]  = {0.2f, 1.0f, 1.0f};
    const float* pcs[3]  = {pc0, pc1, pc2};
    const float* pbds[3] = {pbd0, pbd1, pbd2};
    const int*   eds[3]  = {ed0, ed1, ed2};
    const int*   lis[3]  = {li0, li1, li2};

    const int tid = threadIdx.x;
    const int stride = gridDim.x * 256;
    float ch = 0.f, ed = 0.f, lp = 0.f;

    // index space: [0,90000) gtmin | [90000,93240) predmin |
    //              [93240,102942) edges | [102942,106182) laplace verts
    for (int idx = blockIdx.x * 256 + tid; idx < 106182; idx += stride) {
        if (idx < 90000) {
            ch += gtmin[idx] * (1.0f / 30000.0f);
        } else if (idx < 93240) {
            int p = idx - 90000;
            int m = (p < 156) ? 0 : (p < 774) ? 1 : 2;
            ch += predmin[p] * (1.0f / (float)NVs[m]);
        } else if (idx < 102942) {
            int e = idx - 93240;
            int m = (e < 462) ? 0 : (e < 2310) ? 1 : 2;
            int el = e - eoffs[m];
            const int* E = eds[m];
            const float* P = pcs[m];
            int a = E[2*el], b = E[2*el+1];
            float dx = P[3*a]   - P[3*b];
            float dy = P[3*a+1] - P[3*b+1];
            float dz = P[3*a+2] - P[3*b+2];
            ed += (dx*dx + dy*dy + dz*dz) * (300.0f / (float)NEs[m]);
        } else {
            int v = idx - 102942;
            int m = (v < 156) ? 0 : (v < 774) ? 1 : 2;
            int vl = v - poffs[m];
            const int* L = lis[m];
            const float* PB = pbds[m];
            const float* PC = pcs[m];
            float mvx = PB[3*vl]   - PC[3*vl];
            float mvy = PB[3*vl+1] - PC[3*vl+1];
            float mvz = PB[3*vl+2] - PC[3*vl+2];
            float sx = 0.f, sy = 0.f, sz = 0.f;
            #pragma unroll
            for (int k = 0; k < 8; ++k) {
                int nb = L[10*vl + k];
                if (nb >= 0) {
                    sx += PB[3*nb]   - PC[3*nb];
                    sy += PB[3*nb+1] - PC[3*nb+1];
                    sz += PB[3*nb+2] - PC[3*nb+2];
                }
            }
            float invdeg = 1.0f / (float)L[10*vl + 9];
            float dx = mvx - sx * invdeg;
            float dy = mvy - sy * invdeg;
            float dz = mvz - sz * invdeg;
            float t = dx*dx + dy*dy + dz*dz;
            if (m > 0) t += mvx*mvx + mvy*mvy + mvz*mvz;
            lp += t * (lapc[m] / (float)NVs[m]);
        }
    }

    __shared__ float sred[12];
    for (int off = 32; off; off >>= 1) {
        ch += __shfl_down(ch, off, 64);
        ed += __shfl_down(ed, off, 64);
        lp += __shfl_down(lp, off, 64);
    }
    const int lane = tid & 63, wid = tid >> 6;
    if (lane == 0) { sred[wid] = ch; sred[4 + wid] = ed; sred[8 + wid] = lp; }
    __syncthreads();
    if (tid == 0) {
        partials[blockIdx.x * 4 + 0] = sred[0] + sred[1] + sred[2] + sred[3];
        partials[blockIdx.x * 4 + 1] = sred[4] + sred[5] + sred[6] + sred[7];
        partials[blockIdx.x * 4 + 2] = sred[8] + sred[9] + sred[10] + sred[11];
    }
}

// ---------------------------------------------------------------------------
// Final: sum RB partials, write 4 outputs. 1 block x 128.
// ---------------------------------------------------------------------------
__global__ __launch_bounds__(128) void final_kernel(
    const float* __restrict__ partials, float* __restrict__ out)
{
    const int tid = threadIdx.x;
    float ch = partials[4*tid], ed = partials[4*tid+1], lp = partials[4*tid+2];
    __shared__ float s[6];
    for (int off = 32; off; off >>= 1) {
        ch += __shfl_down(ch, off, 64);
        ed += __shfl_down(ed, off, 64);
        lp += __shfl_down(lp, off, 64);
    }
    if ((tid & 63) == 0) {
        int w = tid >> 6;
        s[w] = ch; s[2 + w] = ed; s[4 + w] = lp;
    }
    __syncthreads();
    if (tid == 0) {
        float c = s[0] + s[1], e = s[2] + s[3], l = s[4] + s[5];
        out[0] = 100.0f * c + 0.1f * e + 0.3f * l;
        out[1] = c;
        out[2] = e;
        out[3] = l;
    }
}

extern "C" void kernel_launch(void* const* d_in, const int* in_sizes, int n_in,
                              void* d_out, int out_size, void* d_ws, size_t ws_size,
                              hipStream_t stream) {
    const float* gt   = (const float*)d_in[0];
    const float* pc0  = (const float*)d_in[1];
    const float* pbd0 = (const float*)d_in[2];
    const int*   ed0  = (const int*)  d_in[3];
    const int*   li0  = (const int*)  d_in[4];
    const float* pc1  = (const float*)d_in[5];
    const float* pbd1 = (const float*)d_in[6];
    const int*   ed1  = (const int*)  d_in[7];
    const int*   li1  = (const int*)  d_in[8];
    const float* pc2  = (const float*)d_in[9];
    const float* pbd2 = (const float*)d_in[10];
    const int*   ed2  = (const int*)  d_in[11];
    const int*   li2  = (const int*)  d_in[12];

    float* ws       = (float*)d_ws;
    float* gtmin    = ws;                    // 3*NGT floats
    float* predmin  = ws + 3 * NGT;          // 3240 floats
    float* partials = ws + 3 * NGT + 3240;   // RB*4 floats
    float* out      = (float*)d_out;

    hipMemsetAsync(gtmin, 0x7f, (3 * NGT + 3240) * sizeof(float), stream);

    dim3 grid(NBLK_G, NCHUNK);
    chamfer_kernel<<<grid, 256, 0, stream>>>(gt, pbd0, pbd1, pbd2, gtmin, predmin);

    partial_kernel<<<RB, 256, 0, stream>>>(pc0, pc1, pc2, pbd0, pbd1, pbd2,
                                           ed0, ed1, ed2, li0, li1, li2,
                                           gtmin, predmin, partials);

    final_kernel<<<1, 128, 0, stream>>>(partials, out);
}